// Round 10
// baseline (328.444 us; speedup 1.0000x reference)
//
#include <hip/hip_runtime.h>

#define NN 4096
#define ALPHA 0.2f
#define FLTMAX 3.402823466e+38f
#define LOG2E 1.44269504088896340736f

typedef __attribute__((ext_vector_type(8))) short short8x;
typedef __attribute__((ext_vector_type(4))) float f32x4;
typedef __attribute__((ext_vector_type(4))) unsigned short ushort4x;
typedef unsigned long long u64;

// round-to-nearest-even f32 -> bf16 bits
__device__ __forceinline__ unsigned short f2bf(float f) {
  unsigned u = __float_as_uint(f);
  u += 0x7fffu + ((u >> 16) & 1u);
  return (unsigned short)(u >> 16);
}
__device__ __forceinline__ float bf2f(unsigned short s) {
  return __uint_as_float(((unsigned)s) << 16);
}
// order-preserving float -> uint key (for atomicMax on floats)
__device__ __forceinline__ unsigned fkey(float f) {
  unsigned b = __float_as_uint(f);
  return (b & 0x80000000u) ? ~b : (b | 0x80000000u);
}
__device__ __forceinline__ float funkey(unsigned k) {
  return __uint_as_float((k & 0x80000000u) ? (k & 0x7fffffffu) : ~k);
}

// ---------------- k0: W -> bf16 hi/lo split Whi/Wlo [d][k]; init dmaxkey ----------------
__global__ __launch_bounds__(256) void k0_prep(
    const float* __restrict__ W, unsigned short* __restrict__ Whi,
    unsigned short* __restrict__ Wlo, unsigned* __restrict__ dmaxkey)
{
  const int t = threadIdx.x;
  const int idx = blockIdx.x * 256 + t;      // 64 blocks: 16384 float4 = 256*256 floats
  float4 v = ((const float4*)W)[idx];
  const float vf[4] = {v.x, v.y, v.z, v.w};
  ushort4x hi, lo;
#pragma unroll
  for (int q = 0; q < 4; ++q) {
    unsigned short hb = f2bf(vf[q]);
    hi[q] = hb;
    lo[q] = f2bf(vf[q] - bf2f(hb));
  }
  ((ushort4x*)Whi)[idx] = hi;
  ((ushort4x*)Wlo)[idx] = lo;
  if (blockIdx.x == 0 && t < 4) dmaxkey[t] = 0x00800000u;  // fkey(-FLTMAX)
}

// ---------------- k1: MFMA Wh = h @ W.T + b (bf16 hi/lo, ~f32 accurate) ----------------
// grid = 256 rowblocks (16 rows) x 4 heads = 1024 blocks; wave w = head-cols 16w..16w+15
// src/dst/dmax stored PRE-SCALED by log2(e) so k3 can use exp2 directly.
__global__ __launch_bounds__(256) void k1_mfma(
    const float* __restrict__ hin, const unsigned short* __restrict__ Whi,
    const unsigned short* __restrict__ Wlo, const float* __restrict__ bias,
    const float* __restrict__ av, unsigned short* __restrict__ WhT,
    float* __restrict__ srcv, float* __restrict__ dstv_soa,
    unsigned* __restrict__ dmaxkey)
{
  __shared__ float lds_s[4][16], lds_d[4][16];
  const int t = threadIdx.x;
  const int rb = blockIdx.x >> 2, h = blockIdx.x & 3;
  const int m0 = rb * 16;
  const int w = t >> 6, l = t & 63, r = l & 15, g = l >> 4;
  const int d = w * 16 + r;              // within-head output dim
  const int col = h * 64 + d;            // global output dim

  f32x4 acc = (f32x4){0.f, 0.f, 0.f, 0.f};
  const float* arow = hin + (size_t)(m0 + r) * 256 + g * 8;   // A: row m0+r, k=8g+j
  const unsigned short* bh = Whi + (size_t)col * 256 + g * 8; // B: col, k=8g+j
  const unsigned short* bl = Wlo + (size_t)col * 256 + g * 8;

#pragma unroll
  for (int ks = 0; ks < 8; ++ks) {       // k0 = 32*ks
    float4 a0 = *(const float4*)(arow + ks * 32);
    float4 a1 = *(const float4*)(arow + ks * 32 + 4);
    const float af[8] = {a0.x, a0.y, a0.z, a0.w, a1.x, a1.y, a1.z, a1.w};
    short8x ahi, alo;
#pragma unroll
    for (int j = 0; j < 8; ++j) {
      unsigned short hb = f2bf(af[j]);
      ahi[j] = (short)hb;
      alo[j] = (short)f2bf(af[j] - bf2f(hb));
    }
    short8x bhf = *(const short8x*)(bh + ks * 32);
    short8x blf = *(const short8x*)(bl + ks * 32);
    acc = __builtin_amdgcn_mfma_f32_16x16x32_bf16(ahi, bhf, acc, 0, 0, 0);
    acc = __builtin_amdgcn_mfma_f32_16x16x32_bf16(ahi, blf, acc, 0, 0, 0);
    acc = __builtin_amdgcn_mfma_f32_16x16x32_bf16(alo, bhf, acc, 0, 0, 0);
  }

  // epilogue: lane holds Wh rows m0+4g+q (q=0..3), col
  const float bc = bias[col];
  const float asrc = av[h * 128 + d];
  const float adst = av[h * 128 + 64 + d];
  float wv[4];
  ushort4x st;
#pragma unroll
  for (int q = 0; q < 4; ++q) {
    wv[q] = acc[q] + bc;
    st[q] = f2bf(wv[q]);
  }
  *(ushort4x*)(WhT + (size_t)col * NN + m0 + 4 * g) = st;

#pragma unroll
  for (int q = 0; q < 4; ++q) {
    float s = wv[q] * asrc, dd = wv[q] * adst;
#pragma unroll
    for (int off = 8; off >= 1; off >>= 1) {     // reduce over 16 cols (lanes r)
      s += __shfl_xor(s, off);
      dd += __shfl_xor(dd, off);
    }
    if (r == 0) { lds_s[w][4 * g + q] = s * LOG2E; lds_d[w][4 * g + q] = dd * LOG2E; }
  }
  __syncthreads();
  if (t < 64) {                                   // wave 0: combine 4 waves
    const int row = t & 15;
    float s = lds_s[0][row] + lds_s[1][row] + lds_s[2][row] + lds_s[3][row];
    float dd = lds_d[0][row] + lds_d[1][row] + lds_d[2][row] + lds_d[3][row];
    if (t < 16) {
      srcv[(size_t)(m0 + row) * 4 + h] = s;
      dstv_soa[(size_t)h * NN + m0 + row] = dd;
    }
    float m = dd;
#pragma unroll
    for (int off = 1; off <= 32; off <<= 1) m = fmaxf(m, __shfl_xor(m, off));
    if (t == 0) atomicMax(dmaxkey + h, fkey(m));
  }
}

// ---------------- k2: adj -> bitmask (pure streaming, wave = row) ----------------
__global__ __launch_bounds__(256) void k2_mask(
    const int* __restrict__ adj, u64* __restrict__ bmask)
{
  const int t = threadIdx.x, wid = t >> 6, l = t & 63;
  const int row = blockIdx.x * 4 + wid;
  const int4* ap = (const int4*)(adj + (size_t)row * NN) + l;
  const int sh = 4 * (l & 15);
#pragma unroll
  for (int it = 0; it < 16; ++it) {
    int4 v = ap[(size_t)it * 64];
    unsigned nib = (v.x & 1) | ((v.y & 1) << 1) | ((v.z & 1) << 2) | ((v.w & 1) << 3);
    u64 w = (u64)nib << sh;
    w |= __shfl_xor(w, 1);
    w |= __shfl_xor(w, 2);
    w |= __shfl_xor(w, 4);
    w |= __shfl_xor(w, 8);
    if ((l & 15) == 0) bmask[(size_t)row * 64 + it * 4 + (l >> 4)] = w;
  }
}

// ---------------- k3: MFMA softmax+PV, s=8 j-splits, XCD-local combos ----------------
// block = (32 rows, head-pair hp, j-split s of 512); waves = (head-sel, j-half of 256)
// blockIdx = rb*16 + (s*2+hp) -> combo pinned to XCD (blockIdx%8), bf16 pacc out.
__global__ __launch_bounds__(256, 6) void k3_mfma(
    const unsigned short* __restrict__ WhT, const float* __restrict__ srcv,
    const float* __restrict__ dstv_soa, const unsigned* __restrict__ dmaxkey,
    const u64* __restrict__ bmask,
    unsigned short* __restrict__ pacc16, float* __restrict__ pden)
{
  __shared__ float lds_acc[2][64][33];   // [hsel][lane][32 acc] pad33: conflict-free
  __shared__ float lds_den[2][64][2];
  const int t = threadIdx.x;
  const int c  = blockIdx.x & 15;
  const int s  = c >> 1, hp = c & 1;
  const int rb = blockIdx.x >> 4;
  const int i0 = rb * 32;
  const int w = t >> 6, l = t & 63;
  const int hsel = w & 1, jh = w >> 1;
  const int h = hp * 2 + hsel;
  const int r = l & 15, g = l >> 4;
  const int j0 = s * 512 + jh * 256;

  const float dmax = funkey(dmaxkey[h]);           // log2-domain
  const float sr0 = srcv[(size_t)(i0 + r) * 4 + h];
  const float sr1 = srcv[(size_t)(i0 + 16 + r) * 4 + h];
  const float x0m = sr0 + dmax, x1m = sr1 + dmax;
  const float mr0 = fmaxf(x0m, ALPHA * x0m);       // lrelu in log2 domain
  const float mr1 = fmaxf(x1m, ALPHA * x1m);
  const float A0 = sr0 - mr0, C0 = ALPHA * sr0 - mr0;  // hoisted row constants
  const float A1 = sr1 - mr1, C1 = ALPHA * sr1 - mr1;

  f32x4 acc[2][4];
#pragma unroll
  for (int m = 0; m < 2; ++m)
#pragma unroll
    for (int n = 0; n < 4; ++n) acc[m][n] = (f32x4){0.f, 0.f, 0.f, 0.f};
  float dacc0 = 0.f, dacc1 = 0.f;

  const unsigned short* whb = WhT + (size_t)(h * 64 + r) * NN + j0 + g * 8;
  const float* dpb = dstv_soa + (size_t)h * NN + j0 + g * 8;
  const u64* mb0 = bmask + (size_t)(i0 + r) * 64 + s * 8 + jh * 4;
  const u64* mb1 = bmask + (size_t)(i0 + 16 + r) * 64 + s * 8 + jh * 4;

  for (int tile = 0; tile < 4; ++tile) {
    const u64 wm0 = mb0[tile];
    const u64 wm1 = mb1[tile];
#pragma unroll
    for (int kt = 0; kt < 2; ++kt) {
      float4 da = *(const float4*)(dpb + tile * 64 + kt * 32);
      float4 db = *(const float4*)(dpb + tile * 64 + kt * 32 + 4);
      const unsigned bits0 = (unsigned)(wm0 >> (kt * 32 + g * 8)) & 0xffu;
      const unsigned bits1 = (unsigned)(wm1 >> (kt * 32 + g * 8)) & 0xffu;
      const float dvs[8] = {da.x, da.y, da.z, da.w, db.x, db.y, db.z, db.w};
      short8x a0, a1;
#pragma unroll
      for (int jj = 0; jj < 8; ++jj) {
        const float dv = dvs[jj];
        const float dva = ALPHA * dv;
        float e0 = fmaxf(A0 + dv, C0 + dva);
        e0 = ((bits0 >> jj) & 1u) ? e0 : -200.0f;
        unsigned pu0 = __float_as_uint(exp2f(e0));
        dacc0 += __uint_as_float(pu0 & 0xffff0000u);   // truncated bf16 = MFMA operand
        a0[jj] = (short)(pu0 >> 16);
        float e1 = fmaxf(A1 + dv, C1 + dva);
        e1 = ((bits1 >> jj) & 1u) ? e1 : -200.0f;
        unsigned pu1 = __float_as_uint(exp2f(e1));
        dacc1 += __uint_as_float(pu1 & 0xffff0000u);
        a1[jj] = (short)(pu1 >> 16);
      }
      short8x bfr[4];
#pragma unroll
      for (int n = 0; n < 4; ++n)
        bfr[n] = *(const short8x*)(whb + (size_t)(n * 16) * NN + tile * 64 + kt * 32);
#pragma unroll
      for (int n = 0; n < 4; ++n) {
        acc[0][n] = __builtin_amdgcn_mfma_f32_16x16x32_bf16(a0, bfr[n], acc[0][n], 0, 0, 0);
        acc[1][n] = __builtin_amdgcn_mfma_f32_16x16x32_bf16(a1, bfr[n], acc[1][n], 0, 0, 0);
      }
    }
  }

  // combine the two j-halves of each head via LDS
  if (jh == 1) {
#pragma unroll
    for (int m = 0; m < 2; ++m)
#pragma unroll
      for (int n = 0; n < 4; ++n)
#pragma unroll
        for (int q = 0; q < 4; ++q)
          lds_acc[hsel][l][m * 16 + n * 4 + q] = acc[m][n][q];
    lds_den[hsel][l][0] = dacc0;
    lds_den[hsel][l][1] = dacc1;
  }
  __syncthreads();
  if (jh == 0) {
#pragma unroll
    for (int m = 0; m < 2; ++m)
#pragma unroll
      for (int n = 0; n < 4; ++n)
#pragma unroll
        for (int q = 0; q < 4; ++q)
          acc[m][n][q] += lds_acc[hsel][l][m * 16 + n * 4 + q];
    dacc0 += lds_den[hsel][l][0];
    dacc1 += lds_den[hsel][l][1];
    // denominator: sum over k-groups (lanes r, r+16, r+32, r+48)
    dacc0 += __shfl_xor(dacc0, 16); dacc0 += __shfl_xor(dacc0, 32);
    dacc1 += __shfl_xor(dacc1, 16); dacc1 += __shfl_xor(dacc1, 32);
    if (l < 16) {
      pden[((size_t)s * NN + i0 + l) * 4 + h] = dacc0;
      pden[((size_t)s * NN + i0 + 16 + l) * 4 + h] = dacc1;
    }
    // C/D: col = l&15, row = 4*(l>>4)+reg
#pragma unroll
    for (int m = 0; m < 2; ++m)
#pragma unroll
      for (int n = 0; n < 4; ++n)
#pragma unroll
        for (int q = 0; q < 4; ++q)
          pacc16[((size_t)s * NN + i0 + 16 * m + g * 4 + q) * 256 + h * 64 + n * 16 + r]
              = f2bf(acc[m][n][q]);
  }
}

// ---------------- k4: combine 8 bf16 partials, divide ----------------
__global__ __launch_bounds__(256) void k4_combine(
    const unsigned short* __restrict__ pacc16, const float* __restrict__ pden,
    float* __restrict__ out)
{
  const int t = threadIdx.x;
  const int i = blockIdx.x * 4 + (t >> 6);
  const int c4 = t & 63;          // ushort4 column index
  const int h = c4 >> 4;
  const ushort4x* pa = (const ushort4x*)pacc16;
  float4 num = {0.f, 0.f, 0.f, 0.f};
  float den = 0.f;
#pragma unroll
  for (int s = 0; s < 8; ++s) {
    ushort4x v = pa[((size_t)(s * NN + i)) * 64 + c4];
    num.x += bf2f(v[0]); num.y += bf2f(v[1]); num.z += bf2f(v[2]); num.w += bf2f(v[3]);
    den += pden[((size_t)s * NN + i) * 4 + h];
  }
  float inv = 1.f / den;
  float4 o = {num.x * inv, num.y * inv, num.z * inv, num.w * inv};
  ((float4*)out)[(size_t)i * 64 + c4] = o;
}

extern "C" void kernel_launch(void* const* d_in, const int* in_sizes, int n_in,
                              void* d_out, int out_size, void* d_ws, size_t ws_size,
                              hipStream_t stream) {
  const float* hin  = (const float*)d_in[0];
  const int*   adj  = (const int*)d_in[1];
  const float* W    = (const float*)d_in[2];
  const float* bias = (const float*)d_in[3];
  const float* av   = (const float*)d_in[4];
  float* out = (float*)d_out;

  char* ws = (char*)d_ws;
  unsigned short* WhT = (unsigned short*)(ws + 0x0);          // 2 MB
  unsigned short* Whi = (unsigned short*)(ws + 0x200000);     // 128 KB
  unsigned short* Wlo = (unsigned short*)(ws + 0x220000);     // 128 KB
  float* srcv  = (float*)(ws + 0x240000);                     // 64 KB
  float* dstv  = (float*)(ws + 0x250000);                     // 64 KB (SoA [4][NN])
  unsigned* dmaxkey = (unsigned*)(ws + 0x260000);             // 16 B (pad)
  u64* bmask   = (u64*)(ws + 0x261000);                       // 2 MB
  unsigned short* pacc16 = (unsigned short*)(ws + 0x461000);  // 16 MB (8 splits, bf16)
  float* pden  = (float*)(ws + 0x1461000);                    // 512 KB

  k0_prep<<<64, 256, 0, stream>>>(W, Whi, Wlo, dmaxkey);
  k1_mfma<<<1024, 256, 0, stream>>>(hin, Whi, Wlo, bias, av, WhT, srcv, dstv, dmaxkey);
  k2_mask<<<1024, 256, 0, stream>>>(adj, bmask);
  k3_mfma<<<2048, 256, 0, stream>>>(WhT, srcv, dstv, dmaxkey, bmask, pacc16, pden);
  k4_combine<<<NN / 4, 256, 0, stream>>>(pacc16, pden, out);
}

// Round 11
// 184.549 us; speedup vs baseline: 1.7797x; 1.7797x over previous
//
#include <hip/hip_runtime.h>

#define NN 4096
#define ALPHA 0.2f
#define FLTMAX 3.402823466e+38f
#define LOG2E 1.44269504088896340736f

typedef __attribute__((ext_vector_type(8))) short short8x;
typedef __attribute__((ext_vector_type(4))) float f32x4;
typedef __attribute__((ext_vector_type(4))) unsigned short ushort4x;
typedef unsigned long long u64;

// round-to-nearest-even f32 -> bf16 bits
__device__ __forceinline__ unsigned short f2bf(float f) {
  unsigned u = __float_as_uint(f);
  u += 0x7fffu + ((u >> 16) & 1u);
  return (unsigned short)(u >> 16);
}
__device__ __forceinline__ float bf2f(unsigned short s) {
  return __uint_as_float(((unsigned)s) << 16);
}
// order-preserving float -> uint key (for atomicMax on floats)
__device__ __forceinline__ unsigned fkey(float f) {
  unsigned b = __float_as_uint(f);
  return (b & 0x80000000u) ? ~b : (b | 0x80000000u);
}
__device__ __forceinline__ float funkey(unsigned k) {
  return __uint_as_float((k & 0x80000000u) ? (k & 0x7fffffffu) : ~k);
}

// ---------------- k0: W -> bf16 hi/lo split Whi/Wlo [d][k]; init dmaxkey ----------------
__global__ __launch_bounds__(256) void k0_prep(
    const float* __restrict__ W, unsigned short* __restrict__ Whi,
    unsigned short* __restrict__ Wlo, unsigned* __restrict__ dmaxkey)
{
  const int t = threadIdx.x;
  const int idx = blockIdx.x * 256 + t;      // 64 blocks: 16384 float4 = 256*256 floats
  float4 v = ((const float4*)W)[idx];
  const float vf[4] = {v.x, v.y, v.z, v.w};
  ushort4x hi, lo;
#pragma unroll
  for (int q = 0; q < 4; ++q) {
    unsigned short hb = f2bf(vf[q]);
    hi[q] = hb;
    lo[q] = f2bf(vf[q] - bf2f(hb));
  }
  ((ushort4x*)Whi)[idx] = hi;
  ((ushort4x*)Wlo)[idx] = lo;
  if (blockIdx.x == 0 && t < 4) dmaxkey[t] = 0x00800000u;  // fkey(-FLTMAX)
}

// ---------------- k1: MFMA Wh = h @ W.T + b (bf16 hi/lo, ~f32 accurate) ----------------
// grid = 256 rowblocks (16 rows) x 4 heads = 1024 blocks; wave w = head-cols 16w..16w+15
// src/dst/dmax stored PRE-SCALED by log2(e) so k3 can use exp2 directly.
__global__ __launch_bounds__(256) void k1_mfma(
    const float* __restrict__ hin, const unsigned short* __restrict__ Whi,
    const unsigned short* __restrict__ Wlo, const float* __restrict__ bias,
    const float* __restrict__ av, unsigned short* __restrict__ WhT,
    float* __restrict__ srcv, float* __restrict__ dstv_soa,
    unsigned* __restrict__ dmaxkey)
{
  __shared__ float lds_s[4][16], lds_d[4][16];
  const int t = threadIdx.x;
  const int rb = blockIdx.x >> 2, h = blockIdx.x & 3;
  const int m0 = rb * 16;
  const int w = t >> 6, l = t & 63, r = l & 15, g = l >> 4;
  const int d = w * 16 + r;              // within-head output dim
  const int col = h * 64 + d;            // global output dim

  f32x4 acc = (f32x4){0.f, 0.f, 0.f, 0.f};
  const float* arow = hin + (size_t)(m0 + r) * 256 + g * 8;   // A: row m0+r, k=8g+j
  const unsigned short* bh = Whi + (size_t)col * 256 + g * 8; // B: col, k=8g+j
  const unsigned short* bl = Wlo + (size_t)col * 256 + g * 8;

#pragma unroll
  for (int ks = 0; ks < 8; ++ks) {       // k0 = 32*ks
    float4 a0 = *(const float4*)(arow + ks * 32);
    float4 a1 = *(const float4*)(arow + ks * 32 + 4);
    const float af[8] = {a0.x, a0.y, a0.z, a0.w, a1.x, a1.y, a1.z, a1.w};
    short8x ahi, alo;
#pragma unroll
    for (int j = 0; j < 8; ++j) {
      unsigned short hb = f2bf(af[j]);
      ahi[j] = (short)hb;
      alo[j] = (short)f2bf(af[j] - bf2f(hb));
    }
    short8x bhf = *(const short8x*)(bh + ks * 32);
    short8x blf = *(const short8x*)(bl + ks * 32);
    acc = __builtin_amdgcn_mfma_f32_16x16x32_bf16(ahi, bhf, acc, 0, 0, 0);
    acc = __builtin_amdgcn_mfma_f32_16x16x32_bf16(ahi, blf, acc, 0, 0, 0);
    acc = __builtin_amdgcn_mfma_f32_16x16x32_bf16(alo, bhf, acc, 0, 0, 0);
  }

  // epilogue: lane holds Wh rows m0+4g+q (q=0..3), col
  const float bc = bias[col];
  const float asrc = av[h * 128 + d];
  const float adst = av[h * 128 + 64 + d];
  float wv[4];
  ushort4x st;
#pragma unroll
  for (int q = 0; q < 4; ++q) {
    wv[q] = acc[q] + bc;
    st[q] = f2bf(wv[q]);
  }
  *(ushort4x*)(WhT + (size_t)col * NN + m0 + 4 * g) = st;

#pragma unroll
  for (int q = 0; q < 4; ++q) {
    float s = wv[q] * asrc, dd = wv[q] * adst;
#pragma unroll
    for (int off = 8; off >= 1; off >>= 1) {     // reduce over 16 cols (lanes r)
      s += __shfl_xor(s, off);
      dd += __shfl_xor(dd, off);
    }
    if (r == 0) { lds_s[w][4 * g + q] = s * LOG2E; lds_d[w][4 * g + q] = dd * LOG2E; }
  }
  __syncthreads();
  if (t < 64) {                                   // wave 0: combine 4 waves
    const int row = t & 15;
    float s = lds_s[0][row] + lds_s[1][row] + lds_s[2][row] + lds_s[3][row];
    float dd = lds_d[0][row] + lds_d[1][row] + lds_d[2][row] + lds_d[3][row];
    if (t < 16) {
      srcv[(size_t)(m0 + row) * 4 + h] = s;
      dstv_soa[(size_t)h * NN + m0 + row] = dd;
    }
    float m = dd;
#pragma unroll
    for (int off = 1; off <= 32; off <<= 1) m = fmaxf(m, __shfl_xor(m, off));
    if (t == 0) atomicMax(dmaxkey + h, fkey(m));
  }
}

// ---------------- k2: adj -> bitmask (pure streaming, wave = row) ----------------
__global__ __launch_bounds__(256) void k2_mask(
    const int* __restrict__ adj, u64* __restrict__ bmask)
{
  const int t = threadIdx.x, wid = t >> 6, l = t & 63;
  const int row = blockIdx.x * 4 + wid;
  const int4* ap = (const int4*)(adj + (size_t)row * NN) + l;
  const int sh = 4 * (l & 15);
#pragma unroll
  for (int it = 0; it < 16; ++it) {
    int4 v = ap[(size_t)it * 64];
    unsigned nib = (v.x & 1) | ((v.y & 1) << 1) | ((v.z & 1) << 2) | ((v.w & 1) << 3);
    u64 w = (u64)nib << sh;
    w |= __shfl_xor(w, 1);
    w |= __shfl_xor(w, 2);
    w |= __shfl_xor(w, 4);
    w |= __shfl_xor(w, 8);
    if ((l & 15) == 0) bmask[(size_t)row * 64 + it * 4 + (l >> 4)] = w;
  }
}

// ---------------- k3: MFMA softmax+PV, s=4 j-splits, XCD-local combos, f32 pacc ----------------
// block = (32 rows, head-pair hp, j-split s of 1024); waves = (head-sel, j-half of 512)
// blockIdx = rb*8 + (s*2+hp) -> combo pinned to XCD (blockIdx%8); full-sector f32 stores.
__global__ __launch_bounds__(256, 4) void k3_mfma(
    const unsigned short* __restrict__ WhT, const float* __restrict__ srcv,
    const float* __restrict__ dstv_soa, const unsigned* __restrict__ dmaxkey,
    const u64* __restrict__ bmask,
    float* __restrict__ pacc, float* __restrict__ pden)
{
  __shared__ float lds_acc[2][64][33];   // [hsel][lane][32 acc] pad33: conflict-free
  __shared__ float lds_den[2][64][2];
  const int t = threadIdx.x;
  const int c  = blockIdx.x & 7;
  const int s  = c >> 1, hp = c & 1;
  const int rb = blockIdx.x >> 3;
  const int i0 = rb * 32;
  const int w = t >> 6, l = t & 63;
  const int hsel = w & 1, jh = w >> 1;
  const int h = hp * 2 + hsel;
  const int r = l & 15, g = l >> 4;
  const int j0 = s * 1024 + jh * 512;

  const float dmax = funkey(dmaxkey[h]);           // log2-domain
  const float sr0 = srcv[(size_t)(i0 + r) * 4 + h];
  const float sr1 = srcv[(size_t)(i0 + 16 + r) * 4 + h];
  const float x0m = sr0 + dmax, x1m = sr1 + dmax;
  const float mr0 = fmaxf(x0m, ALPHA * x0m);       // lrelu in log2 domain
  const float mr1 = fmaxf(x1m, ALPHA * x1m);
  const float A0 = sr0 - mr0, C0 = ALPHA * sr0 - mr0;  // hoisted row constants
  const float A1 = sr1 - mr1, C1 = ALPHA * sr1 - mr1;

  f32x4 acc[2][4];
#pragma unroll
  for (int m = 0; m < 2; ++m)
#pragma unroll
    for (int n = 0; n < 4; ++n) acc[m][n] = (f32x4){0.f, 0.f, 0.f, 0.f};
  float dacc0 = 0.f, dacc1 = 0.f;

  const unsigned short* whb = WhT + (size_t)(h * 64 + r) * NN + j0 + g * 8;
  const float* dpb = dstv_soa + (size_t)h * NN + j0 + g * 8;
  const u64* mb0 = bmask + (size_t)(i0 + r) * 64 + s * 16 + jh * 8;
  const u64* mb1 = bmask + (size_t)(i0 + 16 + r) * 64 + s * 16 + jh * 8;

  for (int tile = 0; tile < 8; ++tile) {
    const u64 wm0 = mb0[tile];
    const u64 wm1 = mb1[tile];
#pragma unroll
    for (int kt = 0; kt < 2; ++kt) {
      float4 da = *(const float4*)(dpb + tile * 64 + kt * 32);
      float4 db = *(const float4*)(dpb + tile * 64 + kt * 32 + 4);
      const unsigned bits0 = (unsigned)(wm0 >> (kt * 32 + g * 8)) & 0xffu;
      const unsigned bits1 = (unsigned)(wm1 >> (kt * 32 + g * 8)) & 0xffu;
      const float dvs[8] = {da.x, da.y, da.z, da.w, db.x, db.y, db.z, db.w};
      short8x a0, a1;
#pragma unroll
      for (int jj = 0; jj < 8; ++jj) {
        const float dv = dvs[jj];
        const float dva = ALPHA * dv;
        float e0 = fmaxf(A0 + dv, C0 + dva);
        e0 = ((bits0 >> jj) & 1u) ? e0 : -200.0f;
        unsigned pu0 = __float_as_uint(exp2f(e0));
        dacc0 += __uint_as_float(pu0 & 0xffff0000u);   // truncated bf16 = MFMA operand
        a0[jj] = (short)(pu0 >> 16);
        float e1 = fmaxf(A1 + dv, C1 + dva);
        e1 = ((bits1 >> jj) & 1u) ? e1 : -200.0f;
        unsigned pu1 = __float_as_uint(exp2f(e1));
        dacc1 += __uint_as_float(pu1 & 0xffff0000u);
        a1[jj] = (short)(pu1 >> 16);
      }
      short8x bfr[4];
#pragma unroll
      for (int n = 0; n < 4; ++n)
        bfr[n] = *(const short8x*)(whb + (size_t)(n * 16) * NN + tile * 64 + kt * 32);
#pragma unroll
      for (int n = 0; n < 4; ++n) {
        acc[0][n] = __builtin_amdgcn_mfma_f32_16x16x32_bf16(a0, bfr[n], acc[0][n], 0, 0, 0);
        acc[1][n] = __builtin_amdgcn_mfma_f32_16x16x32_bf16(a1, bfr[n], acc[1][n], 0, 0, 0);
      }
    }
  }

  // combine the two j-halves of each head via LDS
  if (jh == 1) {
#pragma unroll
    for (int m = 0; m < 2; ++m)
#pragma unroll
      for (int n = 0; n < 4; ++n)
#pragma unroll
        for (int q = 0; q < 4; ++q)
          lds_acc[hsel][l][m * 16 + n * 4 + q] = acc[m][n][q];
    lds_den[hsel][l][0] = dacc0;
    lds_den[hsel][l][1] = dacc1;
  }
  __syncthreads();
  if (jh == 0) {
#pragma unroll
    for (int m = 0; m < 2; ++m)
#pragma unroll
      for (int n = 0; n < 4; ++n)
#pragma unroll
        for (int q = 0; q < 4; ++q)
          acc[m][n][q] += lds_acc[hsel][l][m * 16 + n * 4 + q];
    dacc0 += lds_den[hsel][l][0];
    dacc1 += lds_den[hsel][l][1];
    // denominator: sum over k-groups (lanes r, r+16, r+32, r+48)
    dacc0 += __shfl_xor(dacc0, 16); dacc0 += __shfl_xor(dacc0, 32);
    dacc1 += __shfl_xor(dacc1, 16); dacc1 += __shfl_xor(dacc1, 32);
    if (l < 16) {
      pden[((size_t)s * NN + i0 + l) * 4 + h] = dacc0;
      pden[((size_t)s * NN + i0 + 16 + l) * 4 + h] = dacc1;
    }
    // C/D: col = l&15, row = 4*(l>>4)+reg  (f32 -> full 64B sectors per g-group)
#pragma unroll
    for (int m = 0; m < 2; ++m)
#pragma unroll
      for (int n = 0; n < 4; ++n)
#pragma unroll
        for (int q = 0; q < 4; ++q)
          pacc[((size_t)s * NN + i0 + 16 * m + g * 4 + q) * 256 + h * 64 + n * 16 + r] = acc[m][n][q];
  }
}

// ---------------- k4: combine 4 f32 partials, divide ----------------
__global__ __launch_bounds__(256) void k4_combine(
    const float* __restrict__ pacc, const float* __restrict__ pden,
    float* __restrict__ out)
{
  const int t = threadIdx.x;
  const int i = blockIdx.x * 4 + (t >> 6);
  const int c4 = t & 63;          // float4 column index
  const int h = c4 >> 4;
  const float4* pa = (const float4*)pacc;
  float4 num = {0.f, 0.f, 0.f, 0.f};
  float den = 0.f;
#pragma unroll
  for (int s = 0; s < 4; ++s) {
    float4 v = pa[((size_t)(s * NN + i)) * 64 + c4];
    num.x += v.x; num.y += v.y; num.z += v.z; num.w += v.w;
    den += pden[((size_t)s * NN + i) * 4 + h];
  }
  float inv = 1.f / den;
  float4 o = {num.x * inv, num.y * inv, num.z * inv, num.w * inv};
  ((float4*)out)[(size_t)i * 64 + c4] = o;
}

extern "C" void kernel_launch(void* const* d_in, const int* in_sizes, int n_in,
                              void* d_out, int out_size, void* d_ws, size_t ws_size,
                              hipStream_t stream) {
  const float* hin  = (const float*)d_in[0];
  const int*   adj  = (const int*)d_in[1];
  const float* W    = (const float*)d_in[2];
  const float* bias = (const float*)d_in[3];
  const float* av   = (const float*)d_in[4];
  float* out = (float*)d_out;

  char* ws = (char*)d_ws;
  unsigned short* WhT = (unsigned short*)(ws + 0x0);          // 2 MB
  unsigned short* Whi = (unsigned short*)(ws + 0x200000);     // 128 KB
  unsigned short* Wlo = (unsigned short*)(ws + 0x220000);     // 128 KB
  float* srcv  = (float*)(ws + 0x240000);                     // 64 KB
  float* dstv  = (float*)(ws + 0x250000);                     // 64 KB (SoA [4][NN])
  unsigned* dmaxkey = (unsigned*)(ws + 0x260000);             // 16 B (pad)
  u64* bmask   = (u64*)(ws + 0x261000);                       // 2 MB
  float* pacc  = (float*)(ws + 0x461000);                     // 16 MB (4 splits, f32)
  float* pden  = (float*)(ws + 0x1461000);                    // 256 KB

  k0_prep<<<64, 256, 0, stream>>>(W, Whi, Wlo, dmaxkey);
  k1_mfma<<<1024, 256, 0, stream>>>(hin, Whi, Wlo, bias, av, WhT, srcv, dstv, dmaxkey);
  k2_mask<<<1024, 256, 0, stream>>>(adj, bmask);
  k3_mfma<<<1024, 256, 0, stream>>>(WhT, srcv, dstv, dmaxkey, bmask, pacc, pden);
  k4_combine<<<NN / 4, 256, 0, stream>>>(pacc, pden, out);
}

// Round 12
// 178.719 us; speedup vs baseline: 1.8378x; 1.0326x over previous
//
#include <hip/hip_runtime.h>

#define NN 4096
#define ALPHA 0.2f
#define FLTMAX 3.402823466e+38f
#define LOG2E 1.44269504088896340736f

typedef __attribute__((ext_vector_type(8))) short short8x;
typedef __attribute__((ext_vector_type(4))) float f32x4;
typedef __attribute__((ext_vector_type(4))) unsigned short ushort4x;
typedef __attribute__((ext_vector_type(4))) unsigned uint4x;
typedef unsigned long long u64;

// round-to-nearest-even f32 -> bf16 bits
__device__ __forceinline__ unsigned short f2bf(float f) {
  unsigned u = __float_as_uint(f);
  u += 0x7fffu + ((u >> 16) & 1u);
  return (unsigned short)(u >> 16);
}
__device__ __forceinline__ float bf2f(unsigned short s) {
  return __uint_as_float(((unsigned)s) << 16);
}
// order-preserving float -> uint key (for atomicMax on floats)
__device__ __forceinline__ unsigned fkey(float f) {
  unsigned b = __float_as_uint(f);
  return (b & 0x80000000u) ? ~b : (b | 0x80000000u);
}
__device__ __forceinline__ float funkey(unsigned k) {
  return __uint_as_float((k & 0x80000000u) ? (k & 0x7fffffffu) : ~k);
}
// native 2^x (inputs bounded in [-200, 0]; underflow -> 0 is exact/desired)
__device__ __forceinline__ float exp2v(float x) {
#if __has_builtin(__builtin_amdgcn_exp2f)
  return __builtin_amdgcn_exp2f(x);
#else
  float r;
  asm("v_exp_f32 %0, %1" : "=v"(r) : "v"(x));
  return r;
#endif
}

// ---------------- k0: W -> bf16 hi/lo split Whi/Wlo [d][k]; init dmaxkey ----------------
__global__ __launch_bounds__(256) void k0_prep(
    const float* __restrict__ W, unsigned short* __restrict__ Whi,
    unsigned short* __restrict__ Wlo, unsigned* __restrict__ dmaxkey)
{
  const int t = threadIdx.x;
  const int idx = blockIdx.x * 256 + t;      // 64 blocks: 16384 float4 = 256*256 floats
  float4 v = ((const float4*)W)[idx];
  const float vf[4] = {v.x, v.y, v.z, v.w};
  ushort4x hi, lo;
#pragma unroll
  for (int q = 0; q < 4; ++q) {
    unsigned short hb = f2bf(vf[q]);
    hi[q] = hb;
    lo[q] = f2bf(vf[q] - bf2f(hb));
  }
  ((ushort4x*)Whi)[idx] = hi;
  ((ushort4x*)Wlo)[idx] = lo;
  if (blockIdx.x == 0 && t < 4) dmaxkey[t] = 0x00800000u;  // fkey(-FLTMAX)
}

// ---------------- k1: MFMA Wh = h @ W.T + b (bf16 hi/lo, ~f32 accurate) ----------------
// grid = 256 rowblocks (16 rows) x 4 heads = 1024 blocks; wave w = head-cols 16w..16w+15
// src/dst/dmax stored PRE-SCALED by log2(e) so k3 can use exp2 directly.
__global__ __launch_bounds__(256) void k1_mfma(
    const float* __restrict__ hin, const unsigned short* __restrict__ Whi,
    const unsigned short* __restrict__ Wlo, const float* __restrict__ bias,
    const float* __restrict__ av, unsigned short* __restrict__ WhT,
    float* __restrict__ srcv, float* __restrict__ dstv_soa,
    unsigned* __restrict__ dmaxkey)
{
  __shared__ float lds_s[4][16], lds_d[4][16];
  const int t = threadIdx.x;
  const int rb = blockIdx.x >> 2, h = blockIdx.x & 3;
  const int m0 = rb * 16;
  const int w = t >> 6, l = t & 63, r = l & 15, g = l >> 4;
  const int d = w * 16 + r;              // within-head output dim
  const int col = h * 64 + d;            // global output dim

  f32x4 acc = (f32x4){0.f, 0.f, 0.f, 0.f};
  const float* arow = hin + (size_t)(m0 + r) * 256 + g * 8;   // A: row m0+r, k=8g+j
  const unsigned short* bh = Whi + (size_t)col * 256 + g * 8; // B: col, k=8g+j
  const unsigned short* bl = Wlo + (size_t)col * 256 + g * 8;

#pragma unroll
  for (int ks = 0; ks < 8; ++ks) {       // k0 = 32*ks
    float4 a0 = *(const float4*)(arow + ks * 32);
    float4 a1 = *(const float4*)(arow + ks * 32 + 4);
    const float af[8] = {a0.x, a0.y, a0.z, a0.w, a1.x, a1.y, a1.z, a1.w};
    short8x ahi, alo;
#pragma unroll
    for (int j = 0; j < 8; ++j) {
      unsigned short hb = f2bf(af[j]);
      ahi[j] = (short)hb;
      alo[j] = (short)f2bf(af[j] - bf2f(hb));
    }
    short8x bhf = *(const short8x*)(bh + ks * 32);
    short8x blf = *(const short8x*)(bl + ks * 32);
    acc = __builtin_amdgcn_mfma_f32_16x16x32_bf16(ahi, bhf, acc, 0, 0, 0);
    acc = __builtin_amdgcn_mfma_f32_16x16x32_bf16(ahi, blf, acc, 0, 0, 0);
    acc = __builtin_amdgcn_mfma_f32_16x16x32_bf16(alo, bhf, acc, 0, 0, 0);
  }

  // epilogue: lane holds Wh rows m0+4g+q (q=0..3), col
  const float bc = bias[col];
  const float asrc = av[h * 128 + d];
  const float adst = av[h * 128 + 64 + d];
  float wv[4];
  ushort4x st;
#pragma unroll
  for (int q = 0; q < 4; ++q) {
    wv[q] = acc[q] + bc;
    st[q] = f2bf(wv[q]);
  }
  *(ushort4x*)(WhT + (size_t)col * NN + m0 + 4 * g) = st;

#pragma unroll
  for (int q = 0; q < 4; ++q) {
    float s = wv[q] * asrc, dd = wv[q] * adst;
#pragma unroll
    for (int off = 8; off >= 1; off >>= 1) {     // reduce over 16 cols (lanes r)
      s += __shfl_xor(s, off);
      dd += __shfl_xor(dd, off);
    }
    if (r == 0) { lds_s[w][4 * g + q] = s * LOG2E; lds_d[w][4 * g + q] = dd * LOG2E; }
  }
  __syncthreads();
  if (t < 64) {                                   // wave 0: combine 4 waves
    const int row = t & 15;
    float s = lds_s[0][row] + lds_s[1][row] + lds_s[2][row] + lds_s[3][row];
    float dd = lds_d[0][row] + lds_d[1][row] + lds_d[2][row] + lds_d[3][row];
    if (t < 16) {
      srcv[(size_t)(m0 + row) * 4 + h] = s;
      dstv_soa[(size_t)h * NN + m0 + row] = dd;
    }
    float m = dd;
#pragma unroll
    for (int off = 1; off <= 32; off <<= 1) m = fmaxf(m, __shfl_xor(m, off));
    if (t == 0) atomicMax(dmaxkey + h, fkey(m));
  }
}

// ---------------- k2: adj -> bitmask (pure streaming, wave = row) ----------------
__global__ __launch_bounds__(256) void k2_mask(
    const int* __restrict__ adj, u64* __restrict__ bmask)
{
  const int t = threadIdx.x, wid = t >> 6, l = t & 63;
  const int row = blockIdx.x * 4 + wid;
  const int4* ap = (const int4*)(adj + (size_t)row * NN) + l;
  const int sh = 4 * (l & 15);
#pragma unroll
  for (int it = 0; it < 16; ++it) {
    int4 v = ap[(size_t)it * 64];
    unsigned nib = (v.x & 1) | ((v.y & 1) << 1) | ((v.z & 1) << 2) | ((v.w & 1) << 3);
    u64 w = (u64)nib << sh;
    w |= __shfl_xor(w, 1);
    w |= __shfl_xor(w, 2);
    w |= __shfl_xor(w, 4);
    w |= __shfl_xor(w, 8);
    if ((l & 15) == 0) bmask[(size_t)row * 64 + it * 4 + (l >> 4)] = w;
  }
}

// ---------------- k3: MFMA softmax+PV, s=4 j-splits, XCD-local, MFMA denominator ----------------
// block = (32 rows, head-pair hp, j-split s of 1024); waves = (head-sel, j-half of 512)
// blockIdx = rb*8 + (s*2+hp) -> combo pinned to XCD (blockIdx%8); full-sector f32 stores.
__global__ __launch_bounds__(256, 4) void k3_mfma(
    const unsigned short* __restrict__ WhT, const float* __restrict__ srcv,
    const float* __restrict__ dstv_soa, const unsigned* __restrict__ dmaxkey,
    const u64* __restrict__ bmask,
    float* __restrict__ pacc, float* __restrict__ pden)
{
  __shared__ float lds_acc[2][64][33];   // [hsel][lane][32 acc] pad33: conflict-free
  __shared__ float lds_dv[2][64][9];     // [hsel][lane][8 den]  pad9
  const int t = threadIdx.x;
  const int c  = blockIdx.x & 7;
  const int s  = c >> 1, hp = c & 1;
  const int rb = blockIdx.x >> 3;
  const int i0 = rb * 32;
  const int w = t >> 6, l = t & 63;
  const int hsel = w & 1, jh = w >> 1;
  const int h = hp * 2 + hsel;
  const int r = l & 15, g = l >> 4;
  const int j0 = s * 1024 + jh * 512;

  const float dmax = funkey(dmaxkey[h]);           // log2-domain
  const float sr0 = srcv[(size_t)(i0 + r) * 4 + h];
  const float sr1 = srcv[(size_t)(i0 + 16 + r) * 4 + h];
  const float x0m = sr0 + dmax, x1m = sr1 + dmax;
  const float mr0 = fmaxf(x0m, ALPHA * x0m);       // lrelu in log2 domain
  const float mr1 = fmaxf(x1m, ALPHA * x1m);
  const float A0 = sr0 - mr0, C0 = ALPHA * sr0 - mr0;  // hoisted row constants
  const float A1 = sr1 - mr1, C1 = ALPHA * sr1 - mr1;

  short8x ones;
#pragma unroll
  for (int i = 0; i < 8; ++i) ones[i] = (short)0x3F80;   // bf16 1.0

  f32x4 acc[2][4];
#pragma unroll
  for (int m = 0; m < 2; ++m)
#pragma unroll
    for (int n = 0; n < 4; ++n) acc[m][n] = (f32x4){0.f, 0.f, 0.f, 0.f};
  f32x4 accd0 = (f32x4){0.f, 0.f, 0.f, 0.f};
  f32x4 accd1 = (f32x4){0.f, 0.f, 0.f, 0.f};

  const unsigned short* whb = WhT + (size_t)(h * 64 + r) * NN + j0 + g * 8;
  const float* dpb = dstv_soa + (size_t)h * NN + j0 + g * 8;
  const u64* mb0 = bmask + (size_t)(i0 + r) * 64 + s * 16 + jh * 8;
  const u64* mb1 = bmask + (size_t)(i0 + 16 + r) * 64 + s * 16 + jh * 8;

#pragma unroll 2
  for (int tile = 0; tile < 8; ++tile) {
    const u64 wm0 = mb0[tile];
    const u64 wm1 = mb1[tile];
#pragma unroll
    for (int kt = 0; kt < 2; ++kt) {
      float4 da = *(const float4*)(dpb + tile * 64 + kt * 32);
      float4 db = *(const float4*)(dpb + tile * 64 + kt * 32 + 4);
      const unsigned bits0 = (unsigned)(wm0 >> (kt * 32 + g * 8)) & 0xffu;
      const unsigned bits1 = (unsigned)(wm1 >> (kt * 32 + g * 8)) & 0xffu;
      const float dvs[8] = {da.x, da.y, da.z, da.w, db.x, db.y, db.z, db.w};
      uint4x pk0, pk1;
#pragma unroll
      for (int jp = 0; jp < 4; ++jp) {           // element pair (2jp, 2jp+1)
        const float dva_ = dvs[2 * jp], dvb_ = dvs[2 * jp + 1];
        float e0a = fmaxf(A0 + dva_, fmaf(dva_, ALPHA, C0));
        float e0b = fmaxf(A0 + dvb_, fmaf(dvb_, ALPHA, C0));
        e0a = ((bits0 >> (2 * jp)) & 1u) ? e0a : -200.0f;
        e0b = ((bits0 >> (2 * jp + 1)) & 1u) ? e0b : -200.0f;
        unsigned pa0 = __float_as_uint(exp2v(e0a));
        unsigned pb0 = __float_as_uint(exp2v(e0b));
        pk0[jp] = __builtin_amdgcn_perm(pb0, pa0, 0x07060302);  // [bf16(b)|bf16(a)]
        float e1a = fmaxf(A1 + dva_, fmaf(dva_, ALPHA, C1));
        float e1b = fmaxf(A1 + dvb_, fmaf(dvb_, ALPHA, C1));
        e1a = ((bits1 >> (2 * jp)) & 1u) ? e1a : -200.0f;
        e1b = ((bits1 >> (2 * jp + 1)) & 1u) ? e1b : -200.0f;
        unsigned pa1 = __float_as_uint(exp2v(e1a));
        unsigned pb1 = __float_as_uint(exp2v(e1b));
        pk1[jp] = __builtin_amdgcn_perm(pb1, pa1, 0x07060302);
      }
      const short8x a0 = __builtin_bit_cast(short8x, pk0);
      const short8x a1 = __builtin_bit_cast(short8x, pk1);
      short8x bfr[4];
#pragma unroll
      for (int n = 0; n < 4; ++n)
        bfr[n] = *(const short8x*)(whb + (size_t)(n * 16) * NN + tile * 64 + kt * 32);
#pragma unroll
      for (int n = 0; n < 4; ++n) {
        acc[0][n] = __builtin_amdgcn_mfma_f32_16x16x32_bf16(a0, bfr[n], acc[0][n], 0, 0, 0);
        acc[1][n] = __builtin_amdgcn_mfma_f32_16x16x32_bf16(a1, bfr[n], acc[1][n], 0, 0, 0);
      }
      accd0 = __builtin_amdgcn_mfma_f32_16x16x32_bf16(a0, ones, accd0, 0, 0, 0);
      accd1 = __builtin_amdgcn_mfma_f32_16x16x32_bf16(a1, ones, accd1, 0, 0, 0);
    }
  }

  // combine the two j-halves of each head via LDS
  if (jh == 1) {
#pragma unroll
    for (int m = 0; m < 2; ++m)
#pragma unroll
      for (int n = 0; n < 4; ++n)
#pragma unroll
        for (int q = 0; q < 4; ++q)
          lds_acc[hsel][l][m * 16 + n * 4 + q] = acc[m][n][q];
#pragma unroll
    for (int q = 0; q < 4; ++q) {
      lds_dv[hsel][l][q] = accd0[q];
      lds_dv[hsel][l][4 + q] = accd1[q];
    }
  }
  __syncthreads();
  if (jh == 0) {
#pragma unroll
    for (int m = 0; m < 2; ++m)
#pragma unroll
      for (int n = 0; n < 4; ++n)
#pragma unroll
        for (int q = 0; q < 4; ++q)
          acc[m][n][q] += lds_acc[hsel][l][m * 16 + n * 4 + q];
#pragma unroll
    for (int q = 0; q < 4; ++q) {
      accd0[q] += lds_dv[hsel][l][q];
      accd1[q] += lds_dv[hsel][l][4 + q];
    }
    // denominator: lane l holds rowsum for rows i0+{0,16}+4g+q (all cols equal); r==0 writes
    if (r == 0) {
#pragma unroll
      for (int q = 0; q < 4; ++q) {
        pden[((size_t)s * NN + i0 + 4 * g + q) * 4 + h] = accd0[q];
        pden[((size_t)s * NN + i0 + 16 + 4 * g + q) * 4 + h] = accd1[q];
      }
    }
    // C/D: col = l&15, row = 4*(l>>4)+reg  (f32 -> full 64B sectors per g-group)
#pragma unroll
    for (int m = 0; m < 2; ++m)
#pragma unroll
      for (int n = 0; n < 4; ++n)
#pragma unroll
        for (int q = 0; q < 4; ++q)
          pacc[((size_t)s * NN + i0 + 16 * m + g * 4 + q) * 256 + h * 64 + n * 16 + r] = acc[m][n][q];
  }
}

// ---------------- k4: combine 4 f32 partials, divide ----------------
__global__ __launch_bounds__(256) void k4_combine(
    const float* __restrict__ pacc, const float* __restrict__ pden,
    float* __restrict__ out)
{
  const int t = threadIdx.x;
  const int i = blockIdx.x * 4 + (t >> 6);
  const int c4 = t & 63;          // float4 column index
  const int h = c4 >> 4;
  const float4* pa = (const float4*)pacc;
  float4 num = {0.f, 0.f, 0.f, 0.f};
  float den = 0.f;
#pragma unroll
  for (int s = 0; s < 4; ++s) {
    float4 v = pa[((size_t)(s * NN + i)) * 64 + c4];
    num.x += v.x; num.y += v.y; num.z += v.z; num.w += v.w;
    den += pden[((size_t)s * NN + i) * 4 + h];
  }
  float inv = 1.f / den;
  float4 o = {num.x * inv, num.y * inv, num.z * inv, num.w * inv};
  ((float4*)out)[(size_t)i * 64 + c4] = o;
}

extern "C" void kernel_launch(void* const* d_in, const int* in_sizes, int n_in,
                              void* d_out, int out_size, void* d_ws, size_t ws_size,
                              hipStream_t stream) {
  const float* hin  = (const float*)d_in[0];
  const int*   adj  = (const int*)d_in[1];
  const float* W    = (const float*)d_in[2];
  const float* bias = (const float*)d_in[3];
  const float* av   = (const float*)d_in[4];
  float* out = (float*)d_out;

  char* ws = (char*)d_ws;
  unsigned short* WhT = (unsigned short*)(ws + 0x0);          // 2 MB
  unsigned short* Whi = (unsigned short*)(ws + 0x200000);     // 128 KB
  unsigned short* Wlo = (unsigned short*)(ws + 0x220000);     // 128 KB
  float* srcv  = (float*)(ws + 0x240000);                     // 64 KB
  float* dstv  = (float*)(ws + 0x250000);                     // 64 KB (SoA [4][NN])
  unsigned* dmaxkey = (unsigned*)(ws + 0x260000);             // 16 B (pad)
  u64* bmask   = (u64*)(ws + 0x261000);                       // 2 MB
  float* pacc  = (float*)(ws + 0x461000);                     // 16 MB (4 splits, f32)
  float* pden  = (float*)(ws + 0x1461000);                    // 256 KB

  k0_prep<<<64, 256, 0, stream>>>(W, Whi, Wlo, dmaxkey);
  k1_mfma<<<1024, 256, 0, stream>>>(hin, Whi, Wlo, bias, av, WhT, srcv, dstv, dmaxkey);
  k2_mask<<<1024, 256, 0, stream>>>(adj, bmask);
  k3_mfma<<<1024, 256, 0, stream>>>(WhT, srcv, dstv, dmaxkey, bmask, pacc, pden);
  k4_combine<<<NN / 4, 256, 0, stream>>>(pacc, pden, out);
}